// Round 2
// baseline (512.915 us; speedup 1.0000x reference)
//
#include <hip/hip_runtime.h>
#include <hip/hip_fp16.h>
#include <math.h>

#define HDIM   256
#define QLEN   64
#define NNUM   8
#define NOPS   9
#define NCOLS  16
#define TSTEPS 4

// op indices: SUM=0 COUNT=1 DIFF=2 GREATER=3 LESSER=4 AND=5 OR=6 ASSIGN=7 RESET=8

// ---- workspace layout (float offsets) ----
#define WS_LPIV 0
#define WS_GPIV 1
#define WS_ACOL 2            // [4][16]
#define WS_AOP  66           // [4][9]
#define WS_XP   128          // [64][256] xproj
#define WS_AH   16512        // [256][9]  W_hist[:, :256] @ op_emb.T
#define WS_BH   18816        // [256][16] W_hist[:, 256:512] @ col_emb.T
#define WS_PART 23040        // [NBLK_C][8] block partials (D0..3, N0..3)
#define NBLK_C  2048

typedef _Float16 f16x8 __attribute__((ext_vector_type(8)));
typedef _Float16 f16x4 __attribute__((ext_vector_type(4)));
typedef float    f32x4 __attribute__((ext_vector_type(4)));

__device__ __forceinline__ float fast_tanh(float x) {
    // tanh(x) = 1 - 2/(exp(2x)+1); exp overflow/underflow saturates correctly
    return 1.0f - 2.0f / (__expf(2.0f * x) + 1.0f);
}

// ============================================================================
// Kernel A: parallel precompute — xproj[t][j] = emb[q[t]] . Wx[j,:],
// A_hist[j][o] = W_hist[j,0:256] . op_emb[o,:], B_hist[j][c] = W_hist[j,256:512] . col_emb[c,:]
// ============================================================================
__global__ void precompute_kernel(const int* __restrict__ q,
                                  const float* __restrict__ emb,
                                  const float* __restrict__ Wx,
                                  const float* __restrict__ W_hist,
                                  const float* __restrict__ op_emb,
                                  const float* __restrict__ col_emb,
                                  float* __restrict__ ws) {
    int gid = blockIdx.x * 256 + threadIdx.x;
    if (gid < QLEN * HDIM) {
        int t = gid >> 8, j = gid & 255;
        const float4* x4 = (const float4*)(emb + (size_t)q[t] * HDIM);
        const float4* w4 = (const float4*)(Wx + (size_t)j * HDIM);
        float s = 0.f;
        for (int k = 0; k < HDIM / 4; k++) {
            float4 a = x4[k], b = w4[k];
            s += a.x * b.x + a.y * b.y + a.z * b.z + a.w * b.w;
        }
        ws[WS_XP + t * HDIM + j] = s;
    } else if (gid < QLEN * HDIM + HDIM * NOPS) {
        int idx = gid - QLEN * HDIM;
        int j = idx / NOPS, o = idx % NOPS;
        const float4* w4 = (const float4*)(W_hist + (size_t)j * (3 * HDIM));
        const float4* e4 = (const float4*)(op_emb + (size_t)o * HDIM);
        float s = 0.f;
        for (int k = 0; k < HDIM / 4; k++) {
            float4 a = w4[k], b = e4[k];
            s += a.x * b.x + a.y * b.y + a.z * b.z + a.w * b.w;
        }
        ws[WS_AH + idx] = s;
    } else if (gid < QLEN * HDIM + HDIM * NOPS + HDIM * NCOLS) {
        int idx = gid - QLEN * HDIM - HDIM * NOPS;
        int j = idx / NCOLS, c = idx % NCOLS;
        const float4* w4 = (const float4*)(W_hist + (size_t)j * (3 * HDIM) + HDIM);
        const float4* e4 = (const float4*)(col_emb + (size_t)c * HDIM);
        float s = 0.f;
        for (int k = 0; k < HDIM / 4; k++) {
            float4 a = w4[k], b = e4[k];
            s += a.x * b.x + a.y * b.y + a.z * b.z + a.w * b.w;
        }
        ws[WS_BH + idx] = s;
    }
}

// ============================================================================
// Kernel B: single block, 1024 threads (16 waves).
// Phase 2 (question RNN) runs as an MFMA matvec: wave w owns output rows
// [16w,16w+16); Wh rows live in registers as f16 A-fragments (32 VGPRs);
// h round-trips through a double-buffered f16 LDS buffer. B-frag is a
// broadcast read (all 16 MFMA columns identical), so every lane ends up
// holding the 4 result rows of its quad — no masking needed.
// ============================================================================
__global__ __launch_bounds__(1024, 4) void seq_kernel(
        float* __restrict__ ws,
        const float* __restrict__ Wh,
        const float* __restrict__ U,
        const int* __restrict__ nums,
        const int* __restrict__ lwi,
        const float* __restrict__ W_op,
        const float* __restrict__ W_col,
        const float* __restrict__ W_hist,
        const float* __restrict__ op_emb,
        const float* __restrict__ col_emb) {
    __shared__ float xp[QLEN * HDIM];       // 64 KB
    __shared__ _Float16 hF[2][HDIM];        // double-buffered h (f16, MFMA B source)
    __shared__ float hF32[HDIM];            // h as f32 (becomes q after the loop)
    __shared__ float hs_sel[NNUM * HDIM];   // hidden states at left_word_indices
    __shared__ float zu[16];
    __shared__ float pq_op[HDIM], pq_col[HDIM];
    __shared__ float mh[HDIM], top_op[HDIM], top_col[HDIM];
    __shared__ float logits[32];
    __shared__ float aop_s[NOPS], acol_s[NCOLS];
    __shared__ __half2 hh2[4 * 36];         // h_hist as half2, padded (dword d -> (d>>5)*36 + (d&31))
    __shared__ int lwi_s[NNUM];

    const int tid = threadIdx.x;
    const int wave = tid >> 6, lane = tid & 63;
    const int quad = lane >> 4, qr = lane & 15;
    const int j = tid >> 2, p = tid & 3;    // mapping for phases 3.5/4

    // ---- phase 1: stage xproj to LDS, Wh A-fragments to registers (f16) ----
    for (int i = tid; i < QLEN * HDIM; i += 1024) xp[i] = ws[WS_XP + i];
    f16x8 aW[8];
    {
        int row = 16 * wave + qr;
        const float* wrow = Wh + (size_t)row * HDIM + quad * 8;
        #pragma unroll
        for (int kk = 0; kk < 8; kk++) {
            float4 u0 = *(const float4*)(wrow + kk * 32);
            float4 u1 = *(const float4*)(wrow + kk * 32 + 4);
            f16x8 a;
            a[0] = (_Float16)u0.x; a[1] = (_Float16)u0.y;
            a[2] = (_Float16)u0.z; a[3] = (_Float16)u0.w;
            a[4] = (_Float16)u1.x; a[5] = (_Float16)u1.y;
            a[6] = (_Float16)u1.z; a[7] = (_Float16)u1.w;
            aW[kk] = a;
        }
    }
    if (tid < NNUM) lwi_s[tid] = lwi[tid];
    if (tid < HDIM) hF[0][tid] = (_Float16)0.f;
    __syncthreads();

    // ---- phase 2: question RNN, 64 sequential MFMA-matvec steps ----
    for (int s = 0; s < QLEN; s++) {
        const _Float16* hb = hF[s & 1];
        f32x4 acc = {0.f, 0.f, 0.f, 0.f};
        #pragma unroll
        for (int kk = 0; kk < 8; kk++) {
            f16x8 b = *(const f16x8*)(hb + kk * 32 + quad * 8);   // broadcast read
            acc = __builtin_amdgcn_mfma_f32_16x16x32_f16(aW[kk], b, acc, 0, 0, 0);
        }
        int rb = 16 * wave + quad * 4;       // C/D: row = quad*4 + reg (every lane)
        float4 xb = *(const float4*)(xp + s * HDIM + rb);
        float h0 = fast_tanh(acc[0] + xb.x);
        float h1 = fast_tanh(acc[1] + xb.y);
        float h2 = fast_tanh(acc[2] + xb.z);
        float h3 = fast_tanh(acc[3] + xb.w);
        if (qr == 0) {                       // one writer per quad
            f16x4 hv = {(_Float16)h0, (_Float16)h1, (_Float16)h2, (_Float16)h3};
            *(f16x4*)(&hF[(s + 1) & 1][rb]) = hv;
            *(float4*)(hF32 + rb) = make_float4(h0, h1, h2, h3);
            #pragma unroll
            for (int i = 0; i < NNUM; i++)
                if (lwi_s[i] == s)
                    *(float4*)(hs_sel + i * HDIM + rb) = make_float4(h0, h1, h2, h3);
        }
        __syncthreads();
    }
    // hF32 now holds q

    // ---- phase 3: pivots ----
    {
        int wv = wave, ln = lane;            // 16 waves: wave w -> (i = w>>1, u = w&1)
        int i = wv >> 1, u = wv & 1;
        const float4* z4 = (const float4*)(hs_sel + i * HDIM);
        const float4* u4 = (const float4*)(U + u * HDIM);
        float4 zv = z4[ln], uv = u4[ln];
        float s = zv.x * uv.x + zv.y * uv.y + zv.z * uv.z + zv.w * uv.w;
        #pragma unroll
        for (int off = 32; off >= 1; off >>= 1) s += __shfl_xor(s, off);
        if (ln == 0) zu[wv] = s;
    }
    __syncthreads();
    if (tid == 0) {
        #pragma unroll
        for (int u = 0; u < 2; u++) {
            float mx = -1e30f;
            for (int i = 0; i < NNUM; i++) mx = fmaxf(mx, zu[i * 2 + u]);
            float se = 0.f, pv = 0.f;
            for (int i = 0; i < NNUM; i++) {
                float e = __expf(zu[i * 2 + u] - mx);
                se += e;
                pv += e * (float)nums[i];
            }
            ws[u] = pv / se;   // ws[0]=l_pivot (U[0]), ws[1]=g_pivot (U[1])
        }
    }

    // ---- phase 3.5: q-projections + f16 register cache of h_hist-matrices ----
    {
        const float4* w4 = (const float4*)(W_op + (size_t)j * (2 * HDIM) + p * 64);
        const float4* hq4 = (const float4*)(hF32 + p * 64);
        float s = 0.f;
        #pragma unroll
        for (int i = 0; i < 16; i++) {
            float4 a = w4[i], hv = hq4[i];
            s += a.x * hv.x + a.y * hv.y + a.z * hv.z + a.w * hv.w;
        }
        s += __shfl_xor(s, 1); s += __shfl_xor(s, 2);
        if (p == 0) pq_op[j] = s;
    }
    {
        const float4* w4 = (const float4*)(W_col + (size_t)j * (2 * HDIM) + p * 64);
        const float4* hq4 = (const float4*)(hF32 + p * 64);
        float s = 0.f;
        #pragma unroll
        for (int i = 0; i < 16; i++) {
            float4 a = w4[i], hv = hq4[i];
            s += a.x * hv.x + a.y * hv.y + a.z * hv.z + a.w * hv.w;
        }
        s += __shfl_xor(s, 1); s += __shfl_xor(s, 2);
        if (p == 0) pq_col[j] = s;
    }
    __half2 mop[32], mcol[32], mhist[32];
    {
        const float4* a4 = (const float4*)(W_op   + (size_t)j * (2 * HDIM) + HDIM + p * 64);
        const float4* b4 = (const float4*)(W_col  + (size_t)j * (2 * HDIM) + HDIM + p * 64);
        const float4* c4 = (const float4*)(W_hist + (size_t)j * (3 * HDIM) + 2 * HDIM + p * 64);
        #pragma unroll
        for (int i = 0; i < 16; i++) {
            float4 v = a4[i];
            mop[2*i]   = __floats2half2_rn(v.x, v.y);
            mop[2*i+1] = __floats2half2_rn(v.z, v.w);
            v = b4[i];
            mcol[2*i]   = __floats2half2_rn(v.x, v.y);
            mcol[2*i+1] = __floats2half2_rn(v.z, v.w);
            v = c4[i];
            mhist[2*i]   = __floats2half2_rn(v.x, v.y);
            mhist[2*i+1] = __floats2half2_rn(v.z, v.w);
        }
    }
    if (tid < 144) hh2[tid] = __floats2half2_rn(0.f, 0.f);
    __syncthreads();

    // ---- phase 4: selector chain, T=4 steps ----
    for (int t = 0; t < TSTEPS; t++) {
        float so = 0.f, sc = 0.f, sh = 0.f;
        const __half2* hc = hh2 + p * 36;
        #pragma unroll
        for (int i = 0; i < 32; i++) {
            float2 hv = __half22float2(hc[i]);
            float2 a = __half22float2(mop[i]);
            float2 b = __half22float2(mcol[i]);
            float2 c = __half22float2(mhist[i]);
            so = fmaf(a.x, hv.x, fmaf(a.y, hv.y, so));
            sc = fmaf(b.x, hv.x, fmaf(b.y, hv.y, sc));
            sh = fmaf(c.x, hv.x, fmaf(c.y, hv.y, sh));
        }
        so += __shfl_xor(so, 1); so += __shfl_xor(so, 2);
        sc += __shfl_xor(sc, 1); sc += __shfl_xor(sc, 2);
        sh += __shfl_xor(sh, 1); sh += __shfl_xor(sh, 2);
        if (p == 0) {
            top_op[j]  = fast_tanh(pq_op[j] + so);
            top_col[j] = fast_tanh(pq_col[j] + sc);
            mh[j] = sh;
        }
        __syncthreads();
        // logits: 25 dots of length 256, 32 lanes each
        if (tid < 832) {
            int d = tid >> 5, l = tid & 31;
            int dd = (d < 25) ? d : 24;
            float s = 0.f;
            if (dd < NOPS) {
                const float* e = op_emb + (size_t)dd * HDIM;
                #pragma unroll
                for (int m2 = 0; m2 < 8; m2++) s += e[l * 8 + m2] * top_op[l * 8 + m2];
            } else {
                const float* e = col_emb + (size_t)(dd - NOPS) * HDIM;
                #pragma unroll
                for (int m2 = 0; m2 < 8; m2++) s += e[l * 8 + m2] * top_col[l * 8 + m2];
            }
            s += __shfl_xor(s, 1); s += __shfl_xor(s, 2); s += __shfl_xor(s, 4);
            s += __shfl_xor(s, 8); s += __shfl_xor(s, 16);
            if (l == 0 && d < 25) logits[d] = s;
        }
        __syncthreads();
        if (tid == 0) {
            float mx = -1e30f;
            for (int o = 0; o < NOPS; o++) mx = fmaxf(mx, logits[o]);
            float se = 0.f, e[NOPS];
            for (int o = 0; o < NOPS; o++) { e[o] = __expf(logits[o] - mx); se += e[o]; }
            for (int o = 0; o < NOPS; o++) {
                float a = e[o] / se;
                aop_s[o] = a;
                ws[WS_AOP + t * NOPS + o] = a;
            }
        } else if (tid == 64) {
            float mx = -1e30f;
            for (int c = 0; c < NCOLS; c++) mx = fmaxf(mx, logits[NOPS + c]);
            float se = 0.f, e[NCOLS];
            for (int c = 0; c < NCOLS; c++) { e[c] = __expf(logits[NOPS + c] - mx); se += e[c]; }
            for (int c = 0; c < NCOLS; c++) {
                float a = e[c] / se;
                acol_s[c] = a;
                ws[WS_ACOL + t * NCOLS + c] = a;
            }
        }
        __syncthreads();
        // h_hist update: 128 threads, two elements each (pack into one half2 dword)
        if (tid < 128) {
            float hv01[2];
            #pragma unroll
            for (int hh = 0; hh < 2; hh++) {
                int jj = tid * 2 + hh;
                float s = mh[jj];
                const float* ah = ws + WS_AH + jj * NOPS;
                #pragma unroll
                for (int o = 0; o < NOPS; o++) s += ah[o] * aop_s[o];
                const float* bh = ws + WS_BH + jj * NCOLS;
                #pragma unroll
                for (int c2 = 0; c2 < NCOLS; c2++) s += bh[c2] * acol_s[c2];
                hv01[hh] = fast_tanh(s);
            }
            hh2[(tid >> 5) * 36 + (tid & 31)] = __floats2half2_rn(hv01[0], hv01[1]);
        }
        __syncthreads();
    }
}

// ============================================================================
// Kernel C: fused table pass — sel maps, 4-step rs recursion, coalesced
// lookup write via LDS staging of wa, block-partial reductions for
// D_t = rs^(t).row_sum and N_t = sum rs^(t)
// ============================================================================
__global__ __launch_bounds__(256) void table_kernel(
        const float* __restrict__ table,
        const float* __restrict__ wsc,
        float* __restrict__ wspart,
        float* __restrict__ out,
        int rows) {
    const int tid = threadIdx.x;
    const float lpiv = wsc[WS_LPIV];
    const float gpiv = wsc[WS_GPIV];
    float acolv[TSTEPS][NCOLS];
    float wg[TSTEPS], wl[TSTEPS], wand[TSTEPS], wor[TSTEPS], wrst[TSTEPS], wpass[TSTEPS];
    #pragma unroll
    for (int t = 0; t < TSTEPS; t++) {
        #pragma unroll
        for (int c = 0; c < NCOLS; c++) acolv[t][c] = wsc[WS_ACOL + t * NCOLS + c];
        wg[t]   = wsc[WS_AOP + t * NOPS + 3];
        wl[t]   = wsc[WS_AOP + t * NOPS + 4];
        wand[t] = wsc[WS_AOP + t * NOPS + 5];
        wor[t]  = wsc[WS_AOP + t * NOPS + 6];
        wrst[t] = wsc[WS_AOP + t * NOPS + 8];
        wpass[t] = wsc[WS_AOP + t * NOPS + 0] + wsc[WS_AOP + t * NOPS + 1]
                 + wsc[WS_AOP + t * NOPS + 2] + wsc[WS_AOP + t * NOPS + 7];
    }
    const float wassign = wsc[WS_AOP + 3 * NOPS + 7];
    const float myacol3 = acolv[3][tid & 15];

    float dAcc[TSTEPS] = {0.f, 0.f, 0.f, 0.f};
    float nAcc[TSTEPS] = {0.f, 0.f, 0.f, 0.f};

    __shared__ float waL[2][256];
    int buf = 0;
    const long rowsL = rows;

    for (long cb = (long)blockIdx.x * 256; cb < rowsL; cb += (long)NBLK_C * 256) {
        long r = cb + tid;
        float wa = 0.f;
        if (r < rowsL) {
            const float4* t4 = (const float4*)(table + r * NCOLS);
            float4 v0 = t4[0], v1 = t4[1], v2 = t4[2], v3 = t4[3];
            float tv[NCOLS] = {v0.x, v0.y, v0.z, v0.w, v1.x, v1.y, v1.z, v1.w,
                               v2.x, v2.y, v2.z, v2.w, v3.x, v3.y, v3.z, v3.w};
            float rowsum = 0.f;
            #pragma unroll
            for (int c = 0; c < NCOLS; c++) rowsum += tv[c];
            float dg[TSTEPS] = {0.f, 0.f, 0.f, 0.f};
            float dl[TSTEPS] = {0.f, 0.f, 0.f, 0.f};
            #pragma unroll
            for (int c = 0; c < NCOLS; c++) {
                // sel_g = sigmoid(tv - g_pivot); sel_l = sigmoid(l_pivot - tv)
                float sg = __builtin_amdgcn_rcpf(1.f + __expf(gpiv - tv[c]));
                float sl = __builtin_amdgcn_rcpf(1.f + __expf(tv[c] - lpiv));
                #pragma unroll
                for (int t = 0; t < TSTEPS; t++) {
                    dg[t] = fmaf(sg, acolv[t][c], dg[t]);
                    dl[t] = fmaf(sl, acolv[t][c], dl[t]);
                }
            }
            float rs1 = 1.f, rs2 = 1.f;
            #pragma unroll
            for (int i = 0; i < TSTEPS; i++) {
                dAcc[i] += rs1 * rowsum;
                nAcc[i] += rs1;
                float nrs = wg[i] * dg[i] + wl[i] * dl[i]
                          + wand[i] * fminf(rs1, rs2) + wor[i] * fmaxf(rs1, rs2)
                          + wrst[i] + wpass[i] * rs1;
                rs2 = rs1;
                rs1 = nrs;
            }
            wa = wassign * rs1;   // rs^(4)
        }
        waL[buf][tid] = wa;
        __syncthreads();
        // coalesced write of this chunk's 4096 lookup floats
        const float* wl_ = waL[buf];
        long base = cb * NCOLS;
        #pragma unroll
        for (int k = 0; k < 16; k++) {
            long f = base + k * 256 + tid;
            if (f < rowsL * NCOLS)
                out[1 + f] = wl_[k * 16 + (tid >> 4)] * myacol3;
        }
        buf ^= 1;
    }

    // block reduction of 8 partials
    #pragma unroll
    for (int i = 0; i < TSTEPS; i++) {
        #pragma unroll
        for (int off = 32; off >= 1; off >>= 1) {
            dAcc[i] += __shfl_xor(dAcc[i], off);
            nAcc[i] += __shfl_xor(nAcc[i], off);
        }
    }
    __shared__ float redl[4][8];
    int wv = tid >> 6, ln = tid & 63;
    if (ln == 0) {
        #pragma unroll
        for (int i = 0; i < TSTEPS; i++) {
            redl[wv][i] = dAcc[i];
            redl[wv][4 + i] = nAcc[i];
        }
    }
    __syncthreads();
    if (tid < 8) {
        float s = redl[0][tid] + redl[1][tid] + redl[2][tid] + redl[3][tid];
        wspart[blockIdx.x * 8 + tid] = s;
    }
}

// ============================================================================
// Kernel D: reduce block partials, run the 4-step scalar recurrence
// ============================================================================
__global__ void finalize_kernel(const float* __restrict__ ws, float* __restrict__ out) {
    __shared__ float red[8];
    int a = threadIdx.x >> 5, l = threadIdx.x & 31;
    float s = 0.f;
    for (int b = l; b < NBLK_C; b += 32) s += ws[WS_PART + b * 8 + a];
    s += __shfl_xor(s, 1, 32); s += __shfl_xor(s, 2, 32); s += __shfl_xor(s, 4, 32);
    s += __shfl_xor(s, 8, 32); s += __shfl_xor(s, 16, 32);
    if (l == 0) red[a] = s;
    __syncthreads();
    if (threadIdx.x == 0) {
        float Dv[4] = {red[0], red[1], red[2], red[3]};
        float Nv[4] = {red[4], red[5], red[6], red[7]};
        const float* aop = ws + WS_AOP;
        float sc[5];
        sc[0] = 0.f;
        #pragma unroll
        for (int i = 0; i < 4; i++) {
            float s1 = sc[i];
            float s3 = sc[(i >= 2) ? (i - 2) : 0];
            sc[i + 1] = aop[i * NOPS + 0] * Dv[i] + aop[i * NOPS + 1] * Nv[i]
                      + aop[i * NOPS + 2] * (s3 - s1);
        }
        out[0] = sc[4];
    }
}

// ============================================================================
extern "C" void kernel_launch(void* const* d_in, const int* in_sizes, int n_in,
                              void* d_out, int out_size, void* d_ws, size_t ws_size,
                              hipStream_t stream) {
    const int*   q       = (const int*)d_in[0];
    const int*   nums    = (const int*)d_in[1];
    const int*   lwi     = (const int*)d_in[2];
    const float* table   = (const float*)d_in[3];
    const float* emb     = (const float*)d_in[4];
    const float* Wx      = (const float*)d_in[5];
    const float* Wh      = (const float*)d_in[6];
    const float* W_op    = (const float*)d_in[7];
    const float* op_emb  = (const float*)d_in[8];
    const float* W_col   = (const float*)d_in[9];
    const float* col_emb = (const float*)d_in[10];
    const float* W_hist  = (const float*)d_in[11];
    const float* U       = (const float*)d_in[12];
    float* out = (float*)d_out;
    float* ws  = (float*)d_ws;
    int rows = in_sizes[3] / NCOLS;

    const int pre_outputs = QLEN * HDIM + HDIM * NOPS + HDIM * NCOLS;  // 22784
    precompute_kernel<<<(pre_outputs + 255) / 256, 256, 0, stream>>>(
        q, emb, Wx, W_hist, op_emb, col_emb, ws);
    seq_kernel<<<1, 1024, 0, stream>>>(
        ws, Wh, U, nums, lwi, W_op, W_col, W_hist, op_emb, col_emb);
    table_kernel<<<NBLK_C, 256, 0, stream>>>(
        table, ws, ws + WS_PART, out, rows);
    finalize_kernel<<<1, 256, 0, stream>>>(ws, out);
}

// Round 4
// 325.563 us; speedup vs baseline: 1.5755x; 1.5755x over previous
//
#include <hip/hip_runtime.h>
#include <hip/hip_fp16.h>
#include <math.h>

#define HDIM   256
#define QLEN   64
#define NNUM   8
#define NOPS   9
#define NCOLS  16
#define TSTEPS 4

// op indices: SUM=0 COUNT=1 DIFF=2 GREATER=3 LESSER=4 AND=5 OR=6 ASSIGN=7 RESET=8

// ---- workspace layout (float offsets) ----
#define WS_LPIV 0
#define WS_GPIV 1
#define WS_ACOL 2            // [4][16]
#define WS_AOP  66           // [4][9]
#define WS_Q    112          // [256] final question RNN state q
#define WS_PQO  368          // [256] W_op[:, :256] @ q
#define WS_PQC  624          // [256] W_col[:, :256] @ q
#define WS_HS   880          // [8][256] hidden states at left_word_indices
#define WS_XP   2928         // [64][256] xproj
#define WS_AH   19312        // [256][9]  W_hist[:, :256] @ op_emb.T
#define WS_BH   21616        // [256][16] W_hist[:, 256:512] @ col_emb.T
#define WS_WH16 25712        // Wh as f16, MFMA-fragment order (32768 halfs = 16384 f)
#define WS_M16  42096        // 3x 256x256 f16 (h-side of W_op/W_col/W_hist): 98304 floats
#define WS_PART 140400       // [NBLK_C][8] block partials (D0..3, N0..3)
#define NBLK_C  2048

typedef _Float16 f16x8 __attribute__((ext_vector_type(8)));
typedef _Float16 f16x4 __attribute__((ext_vector_type(4)));
typedef float    f32x4 __attribute__((ext_vector_type(4)));

__device__ __forceinline__ float fast_tanh(float x) {
    return 1.0f - 2.0f / (__expf(2.0f * x) + 1.0f);
}

// ============================================================================
// Kernel A: parallel precompute.
//  gid ranges:
//   [0, 16384)              xproj[t][j] = emb[q[t]] . Wx[j,:]
//   [16384, 18688)          AH[j][o]  = W_hist[j,0:256] . op_emb[o,:]
//   [18688, 22784)          BH[j][c]  = W_hist[j,256:512] . col_emb[c,:]
//   [22784, 39168)          Wh -> f16 fragment-order pack (dwords)
//   [39168, 137472)         W_op/W_col/W_hist h-side halves -> f16 pack
//                           (32768 dwords = 65536 halfs per matrix)
// ============================================================================
__global__ void precompute_kernel(const int* __restrict__ q,
                                  const float* __restrict__ emb,
                                  const float* __restrict__ Wx,
                                  const float* __restrict__ Wh,
                                  const float* __restrict__ W_op,
                                  const float* __restrict__ W_col,
                                  const float* __restrict__ W_hist,
                                  const float* __restrict__ op_emb,
                                  const float* __restrict__ col_emb,
                                  float* __restrict__ ws) {
    int gid = blockIdx.x * 256 + threadIdx.x;
    if (gid < QLEN * HDIM) {
        int t = gid >> 8, j = gid & 255;
        const float4* x4 = (const float4*)(emb + (size_t)q[t] * HDIM);
        const float4* w4 = (const float4*)(Wx + (size_t)j * HDIM);
        float s = 0.f;
        for (int k = 0; k < HDIM / 4; k++) {
            float4 a = x4[k], b = w4[k];
            s += a.x * b.x + a.y * b.y + a.z * b.z + a.w * b.w;
        }
        ws[WS_XP + t * HDIM + j] = s;
    } else if (gid < QLEN * HDIM + HDIM * NOPS) {
        int idx = gid - QLEN * HDIM;
        int j = idx / NOPS, o = idx % NOPS;
        const float4* w4 = (const float4*)(W_hist + (size_t)j * (3 * HDIM));
        const float4* e4 = (const float4*)(op_emb + (size_t)o * HDIM);
        float s = 0.f;
        for (int k = 0; k < HDIM / 4; k++) {
            float4 a = w4[k], b = e4[k];
            s += a.x * b.x + a.y * b.y + a.z * b.z + a.w * b.w;
        }
        ws[WS_AH + idx] = s;
    } else if (gid < QLEN * HDIM + HDIM * NOPS + HDIM * NCOLS) {
        int idx = gid - QLEN * HDIM - HDIM * NOPS;
        int j = idx / NCOLS, c = idx % NCOLS;
        const float4* w4 = (const float4*)(W_hist + (size_t)j * (3 * HDIM) + HDIM);
        const float4* e4 = (const float4*)(col_emb + (size_t)c * HDIM);
        float s = 0.f;
        for (int k = 0; k < HDIM / 4; k++) {
            float4 a = w4[k], b = e4[k];
            s += a.x * b.x + a.y * b.y + a.z * b.z + a.w * b.w;
        }
        ws[WS_BH + idx] = s;
    } else if (gid < 22784 + 16384) {
        // Wh f16 pack: half-index = (((w*8+kk)*4+quad)*16+qr)*8 + e,
        // value = Wh[16w+qr][kk*32 + quad*8 + e]
        int did = gid - 22784;
        int hidx = did * 2;
        int e = hidx & 7, qr = (hidx >> 3) & 15, quad = (hidx >> 7) & 3;
        int kk = (hidx >> 9) & 7, w = hidx >> 12;
        const float* src = Wh + (size_t)(16 * w + qr) * HDIM + kk * 32 + quad * 8 + e;
        float2 v = *(const float2*)src;
        ((__half2*)(ws + WS_WH16))[did] = __floats2half2_rn(v.x, v.y);
    } else if (gid < 22784 + 16384 + 98304) {
        // M16 pack: mat m = did>>15 (32768 dwords = 65536 halfs per mat),
        // within-mat half-index = ((i)*256 + j)*8 + e  (i in [0,32)),
        // value = W_m[j][off_m + i*8 + e]
        int did = gid - (22784 + 16384);
        int mat = did >> 15;
        int hidx = (did & 32767) * 2;
        int e = hidx & 7, j = (hidx >> 3) & 255, i = hidx >> 11;
        const float* src;
        if (mat == 0)      src = W_op   + (size_t)j * (2 * HDIM) + HDIM     + i * 8 + e;
        else if (mat == 1) src = W_col  + (size_t)j * (2 * HDIM) + HDIM     + i * 8 + e;
        else               src = W_hist + (size_t)j * (3 * HDIM) + 2 * HDIM + i * 8 + e;
        float2 v = *(const float2*)src;
        ((__half2*)(ws + WS_M16))[did] = __floats2half2_rn(v.x, v.y);
    }
}

// ============================================================================
// Kernel B1: single block, 1024 threads (16 waves) — question RNN only.
// Wave w owns rows [16w,16w+16); Wh fragments read pre-packed f16 from ws.
// Writes q and hs_sel (f32) to ws.
// ============================================================================
__global__ __launch_bounds__(1024) void rnn_kernel(
        float* __restrict__ ws,
        const int* __restrict__ lwi) {
    __shared__ _Float16 hF[2][HDIM];
    __shared__ float hF32[HDIM];
    __shared__ int lwi_s[NNUM];

    const int tid = threadIdx.x;
    const int wave = tid >> 6, lane = tid & 63;
    const int quad = lane >> 4, qr = lane & 15;

    // Wh fragments: per (wave,kk) the 64 lanes read 1 KB contiguous
    const _Float16* wsh = (const _Float16*)(ws + WS_WH16);
    f16x8 aW[8];
    #pragma unroll
    for (int kk = 0; kk < 8; kk++)
        aW[kk] = *(const f16x8*)(wsh + ((size_t)((wave * 8 + kk) * 64 + lane)) * 8);

    if (tid < NNUM) lwi_s[tid] = lwi[tid];
    if (tid < HDIM) hF[0][tid] = (_Float16)0.f;
    __syncthreads();

    const int rb = 16 * wave + quad * 4;   // C/D rows this lane holds
    for (int s = 0; s < QLEN; s++) {
        // prefetch x-projection (independent of h)
        float4 xb = *(const float4*)(ws + WS_XP + s * HDIM + rb);
        const _Float16* hb = hF[s & 1];
        f32x4 acc = {0.f, 0.f, 0.f, 0.f};
        #pragma unroll
        for (int kk = 0; kk < 8; kk++) {
            f16x8 b = *(const f16x8*)(hb + kk * 32 + quad * 8);   // broadcast read
            acc = __builtin_amdgcn_mfma_f32_16x16x32_f16(aW[kk], b, acc, 0, 0, 0);
        }
        float h0 = fast_tanh(acc[0] + xb.x);
        float h1 = fast_tanh(acc[1] + xb.y);
        float h2 = fast_tanh(acc[2] + xb.z);
        float h3 = fast_tanh(acc[3] + xb.w);
        if (qr == 0) {
            f16x4 hv = {(_Float16)h0, (_Float16)h1, (_Float16)h2, (_Float16)h3};
            *(f16x4*)(&hF[(s + 1) & 1][rb]) = hv;
            if (s == QLEN - 1) *(float4*)(hF32 + rb) = make_float4(h0, h1, h2, h3);
            #pragma unroll
            for (int i = 0; i < NNUM; i++)
                if (lwi_s[i] == s)
                    *(float4*)(ws + WS_HS + i * HDIM + rb) = make_float4(h0, h1, h2, h3);
        }
        __syncthreads();
    }
    if (tid < 64) *(float4*)(ws + WS_Q + tid * 4) = *(const float4*)(hF32 + tid * 4);
}

// ============================================================================
// Kernel P2: parallel q-projections — pq_op[j] = W_op[j,:256].q,
// pq_col[j] = W_col[j,:256].q.  512 dots x 32 lanes = 64 blocks x 256.
// ============================================================================
__global__ void qproj_kernel(const float* __restrict__ W_op,
                             const float* __restrict__ W_col,
                             float* __restrict__ ws) {
    int gid = blockIdx.x * 256 + threadIdx.x;
    int dot = gid >> 5, l = gid & 31;
    int mat = dot >> 8, j = dot & 255;
    const float* w = (mat ? W_col : W_op) + (size_t)j * (2 * HDIM) + l * 8;
    const float* qv = ws + WS_Q + l * 8;
    float4 a0 = *(const float4*)w,        a1 = *(const float4*)(w + 4);
    float4 b0 = *(const float4*)qv,       b1 = *(const float4*)(qv + 4);
    float s = a0.x * b0.x + a0.y * b0.y + a0.z * b0.z + a0.w * b0.w
            + a1.x * b1.x + a1.y * b1.y + a1.z * b1.z + a1.w * b1.w;
    s += __shfl_xor(s, 1); s += __shfl_xor(s, 2); s += __shfl_xor(s, 4);
    s += __shfl_xor(s, 8); s += __shfl_xor(s, 16);
    if (l == 0) ws[(mat ? WS_PQC : WS_PQO) + j] = s;
}

// ============================================================================
// Kernel B2: single block, 256 threads — pivots + selector chain (T=4).
// h-side matrices read as f16 from ws (L2-resident after first t).
// ============================================================================
__global__ __launch_bounds__(256) void select_kernel(
        float* __restrict__ ws,
        const float* __restrict__ U,
        const int* __restrict__ nums,
        const float* __restrict__ op_emb,
        const float* __restrict__ col_emb) {
    __shared__ float zu[16];
    __shared__ float hH[HDIM];
    __shared__ float top_op[HDIM], top_col[HDIM], mh[HDIM];
    __shared__ float logits[32];
    __shared__ float aop_s[NOPS], acol_s[NCOLS];

    const int tid = threadIdx.x;

    // ---- pivots: 16 dots (i in [0,8), u in {0,1}), 16 lanes each ----
    {
        int g = tid >> 4, l = tid & 15;
        int i = g >> 1, u = g & 1;
        const float* z = ws + WS_HS + i * HDIM + l * 16;
        const float* uu = U + u * HDIM + l * 16;
        float s = 0.f;
        #pragma unroll
        for (int k = 0; k < 4; k++) {
            float4 a = *(const float4*)(z + k * 4), b = *(const float4*)(uu + k * 4);
            s += a.x * b.x + a.y * b.y + a.z * b.z + a.w * b.w;
        }
        s += __shfl_xor(s, 1); s += __shfl_xor(s, 2);
        s += __shfl_xor(s, 4); s += __shfl_xor(s, 8);
        if (l == 0) zu[g] = s;
    }
    if (tid < HDIM) hH[tid] = 0.f;
    __syncthreads();
    if (tid == 0) {
        #pragma unroll
        for (int u = 0; u < 2; u++) {
            float mx = -1e30f;
            for (int i = 0; i < NNUM; i++) mx = fmaxf(mx, zu[i * 2 + u]);
            float se = 0.f, pv = 0.f;
            for (int i = 0; i < NNUM; i++) {
                float e = __expf(zu[i * 2 + u] - mx);
                se += e;
                pv += e * (float)nums[i];
            }
            ws[u] = pv / se;
        }
    }
    __syncthreads();

    const _Float16* wsm = (const _Float16*)(ws + WS_M16);
    const float pqo = ws[WS_PQO + tid];
    const float pqc = ws[WS_PQC + tid];

    for (int t = 0; t < TSTEPS; t++) {
        // three 256-length dots with h for row tid; matrices re-read from L2
        float so = 0.f, sc = 0.f, sh = 0.f;
        #pragma unroll
        for (int i = 0; i < 32; i++) {
            float4 h0 = *(const float4*)(hH + i * 8);
            float4 h1 = *(const float4*)(hH + i * 8 + 4);
            f16x8 a = *(const f16x8*)(wsm + ((size_t)(0 * 32 + i) * 256 + tid) * 8);
            f16x8 b = *(const f16x8*)(wsm + ((size_t)(1 * 32 + i) * 256 + tid) * 8);
            f16x8 c = *(const f16x8*)(wsm + ((size_t)(2 * 32 + i) * 256 + tid) * 8);
            so += (float)a[0]*h0.x + (float)a[1]*h0.y + (float)a[2]*h0.z + (float)a[3]*h0.w
                + (float)a[4]*h1.x + (float)a[5]*h1.y + (float)a[6]*h1.z + (float)a[7]*h1.w;
            sc += (float)b[0]*h0.x + (float)b[1]*h0.y + (float)b[2]*h0.z + (float)b[3]*h0.w
                + (float)b[4]*h1.x + (float)b[5]*h1.y + (float)b[6]*h1.z + (float)b[7]*h1.w;
            sh += (float)c[0]*h0.x + (float)c[1]*h0.y + (float)c[2]*h0.z + (float)c[3]*h0.w
                + (float)c[4]*h1.x + (float)c[5]*h1.y + (float)c[6]*h1.z + (float)c[7]*h1.w;
        }
        top_op[tid]  = fast_tanh(pqo + so);
        top_col[tid] = fast_tanh(pqc + sc);
        mh[tid] = sh;
        __syncthreads();

        // logits: 25 dots of 256, 32 lanes each, 8 groups per pass
        #pragma unroll
        for (int d0 = 0; d0 < 32; d0 += 8) {
            int d = d0 + (tid >> 5), l = tid & 31;
            if (d < 25) {
                float s = 0.f;
                if (d < NOPS) {
                    const float* e = op_emb + (size_t)d * HDIM;
                    #pragma unroll
                    for (int m = 0; m < 8; m++) s += e[l * 8 + m] * top_op[l * 8 + m];
                } else {
                    const float* e = col_emb + (size_t)(d - NOPS) * HDIM;
                    #pragma unroll
                    for (int m = 0; m < 8; m++) s += e[l * 8 + m] * top_col[l * 8 + m];
                }
                s += __shfl_xor(s, 1); s += __shfl_xor(s, 2); s += __shfl_xor(s, 4);
                s += __shfl_xor(s, 8); s += __shfl_xor(s, 16);
                if (l == 0) logits[d] = s;
            }
        }
        __syncthreads();
        if (tid == 0) {
            float mx = -1e30f;
            for (int o = 0; o < NOPS; o++) mx = fmaxf(mx, logits[o]);
            float se = 0.f, e[NOPS];
            for (int o = 0; o < NOPS; o++) { e[o] = __expf(logits[o] - mx); se += e[o]; }
            for (int o = 0; o < NOPS; o++) {
                float a = e[o] / se;
                aop_s[o] = a;
                ws[WS_AOP + t * NOPS + o] = a;
            }
        } else if (tid == 32) {
            float mx = -1e30f;
            for (int c = 0; c < NCOLS; c++) mx = fmaxf(mx, logits[NOPS + c]);
            float se = 0.f, e[NCOLS];
            for (int c = 0; c < NCOLS; c++) { e[c] = __expf(logits[NOPS + c] - mx); se += e[c]; }
            for (int c = 0; c < NCOLS; c++) {
                float a = e[c] / se;
                acol_s[c] = a;
                ws[WS_ACOL + t * NCOLS + c] = a;
            }
        }
        __syncthreads();
        // h_hist update (all 256 rows, one per thread)
        {
            float s = mh[tid];
            const float* ah = ws + WS_AH + tid * NOPS;
            #pragma unroll
            for (int o = 0; o < NOPS; o++) s += ah[o] * aop_s[o];
            const float* bh = ws + WS_BH + tid * NCOLS;
            #pragma unroll
            for (int c = 0; c < NCOLS; c++) s += bh[c] * acol_s[c];
            float hv = fast_tanh(s);
            __syncthreads();
            hH[tid] = hv;
        }
        __syncthreads();
    }
}

// ============================================================================
// Kernel C: fused table pass — sel maps, 4-step rs recursion, lookup write,
// block-partial reductions for D_t = rs^(t).row_sum and N_t = sum rs^(t)
// ============================================================================
__global__ __launch_bounds__(256) void table_kernel(
        const float* __restrict__ table,
        const float* __restrict__ wsc,
        float* __restrict__ wspart,
        float* __restrict__ out,
        int rows) {
    const int tid = threadIdx.x;
    const float lpiv = wsc[WS_LPIV];
    const float gpiv = wsc[WS_GPIV];
    float acolv[TSTEPS][NCOLS];
    float wg[TSTEPS], wl[TSTEPS], wand[TSTEPS], wor[TSTEPS], wrst[TSTEPS], wpass[TSTEPS];
    #pragma unroll
    for (int t = 0; t < TSTEPS; t++) {
        #pragma unroll
        for (int c = 0; c < NCOLS; c++) acolv[t][c] = wsc[WS_ACOL + t * NCOLS + c];
        wg[t]   = wsc[WS_AOP + t * NOPS + 3];
        wl[t]   = wsc[WS_AOP + t * NOPS + 4];
        wand[t] = wsc[WS_AOP + t * NOPS + 5];
        wor[t]  = wsc[WS_AOP + t * NOPS + 6];
        wrst[t] = wsc[WS_AOP + t * NOPS + 8];
        wpass[t] = wsc[WS_AOP + t * NOPS + 0] + wsc[WS_AOP + t * NOPS + 1]
                 + wsc[WS_AOP + t * NOPS + 2] + wsc[WS_AOP + t * NOPS + 7];
    }
    const float wassign = wsc[WS_AOP + 3 * NOPS + 7];

    float dAcc[TSTEPS] = {0.f, 0.f, 0.f, 0.f};
    float nAcc[TSTEPS] = {0.f, 0.f, 0.f, 0.f};

    for (int r = blockIdx.x * 256 + tid; r < rows; r += NBLK_C * 256) {
        const float4* t4 = (const float4*)(table + (size_t)r * NCOLS);
        float4 v0 = t4[0], v1 = t4[1], v2 = t4[2], v3 = t4[3];
        float tv[NCOLS] = {v0.x, v0.y, v0.z, v0.w, v1.x, v1.y, v1.z, v1.w,
                           v2.x, v2.y, v2.z, v2.w, v3.x, v3.y, v3.z, v3.w};
        float rowsum = 0.f;
        #pragma unroll
        for (int c = 0; c < NCOLS; c++) rowsum += tv[c];
        float dg[TSTEPS] = {0.f, 0.f, 0.f, 0.f};
        float dl[TSTEPS] = {0.f, 0.f, 0.f, 0.f};
        #pragma unroll
        for (int c = 0; c < NCOLS; c++) {
            float sg = __builtin_amdgcn_rcpf(1.f + __expf(gpiv - tv[c]));
            float sl = __builtin_amdgcn_rcpf(1.f + __expf(tv[c] - lpiv));
            #pragma unroll
            for (int t = 0; t < TSTEPS; t++) {
                dg[t] = fmaf(sg, acolv[t][c], dg[t]);
                dl[t] = fmaf(sl, acolv[t][c], dl[t]);
            }
        }
        float rs1 = 1.f, rs2 = 1.f;
        #pragma unroll
        for (int i = 0; i < TSTEPS; i++) {
            dAcc[i] += rs1 * rowsum;
            nAcc[i] += rs1;
            float nrs = wg[i] * dg[i] + wl[i] * dl[i]
                      + wand[i] * fminf(rs1, rs2) + wor[i] * fmaxf(rs1, rs2)
                      + wrst[i] + wpass[i] * rs1;
            rs2 = rs1;
            rs1 = nrs;
        }
        float wa = wassign * rs1;   // rs^(4)
        float* ob = out + 1 + (size_t)r * NCOLS;
        #pragma unroll
        for (int c = 0; c < NCOLS; c++) ob[c] = wa * acolv[3][c];
    }

    #pragma unroll
    for (int i = 0; i < TSTEPS; i++) {
        #pragma unroll
        for (int off = 32; off >= 1; off >>= 1) {
            dAcc[i] += __shfl_xor(dAcc[i], off);
            nAcc[i] += __shfl_xor(nAcc[i], off);
        }
    }
    __shared__ float redl[4][8];
    int wv = tid >> 6, ln = tid & 63;
    if (ln == 0) {
        #pragma unroll
        for (int i = 0; i < TSTEPS; i++) {
            redl[wv][i] = dAcc[i];
            redl[wv][4 + i] = nAcc[i];
        }
    }
    __syncthreads();
    if (tid < 8) {
        float s = redl[0][tid] + redl[1][tid] + redl[2][tid] + redl[3][tid];
        wspart[blockIdx.x * 8 + tid] = s;
    }
}

// ============================================================================
// Kernel D: reduce block partials, run the 4-step scalar recurrence
// ============================================================================
__global__ void finalize_kernel(const float* __restrict__ ws, float* __restrict__ out) {
    __shared__ float red[8];
    int a = threadIdx.x >> 5, l = threadIdx.x & 31;
    float s = 0.f;
    for (int b = l; b < NBLK_C; b += 32) s += ws[WS_PART + b * 8 + a];
    s += __shfl_xor(s, 1, 32); s += __shfl_xor(s, 2, 32); s += __shfl_xor(s, 4, 32);
    s += __shfl_xor(s, 8, 32); s += __shfl_xor(s, 16, 32);
    if (l == 0) red[a] = s;
    __syncthreads();
    if (threadIdx.x == 0) {
        float Dv[4] = {red[0], red[1], red[2], red[3]};
        float Nv[4] = {red[4], red[5], red[6], red[7]};
        const float* aop = ws + WS_AOP;
        float sc[5];
        sc[0] = 0.f;
        #pragma unroll
        for (int i = 0; i < 4; i++) {
            float s1 = sc[i];
            float s3 = sc[(i >= 2) ? (i - 2) : 0];
            sc[i + 1] = aop[i * NOPS + 0] * Dv[i] + aop[i * NOPS + 1] * Nv[i]
                      + aop[i * NOPS + 2] * (s3 - s1);
        }
        out[0] = sc[4];
    }
}

// ============================================================================
extern "C" void kernel_launch(void* const* d_in, const int* in_sizes, int n_in,
                              void* d_out, int out_size, void* d_ws, size_t ws_size,
                              hipStream_t stream) {
    const int*   q       = (const int*)d_in[0];
    const int*   nums    = (const int*)d_in[1];
    const int*   lwi     = (const int*)d_in[2];
    const float* table   = (const float*)d_in[3];
    const float* emb     = (const float*)d_in[4];
    const float* Wx      = (const float*)d_in[5];
    const float* Wh      = (const float*)d_in[6];
    const float* W_op    = (const float*)d_in[7];
    const float* op_emb  = (const float*)d_in[8];
    const float* W_col   = (const float*)d_in[9];
    const float* col_emb = (const float*)d_in[10];
    const float* W_hist  = (const float*)d_in[11];
    const float* U       = (const float*)d_in[12];
    float* out = (float*)d_out;
    float* ws  = (float*)d_ws;
    int rows = in_sizes[3] / NCOLS;

    const int pre_outputs = 137472;   // see precompute_kernel gid map
    precompute_kernel<<<(pre_outputs + 255) / 256, 256, 0, stream>>>(
        q, emb, Wx, Wh, W_op, W_col, W_hist, op_emb, col_emb, ws);
    rnn_kernel<<<1, 1024, 0, stream>>>(ws, lwi);
    qproj_kernel<<<64, 256, 0, stream>>>(W_op, W_col, ws);
    select_kernel<<<1, 256, 0, stream>>>(ws, U, nums, op_emb, col_emb);
    table_kernel<<<NBLK_C, 256, 0, stream>>>(
        table, ws, ws + WS_PART, out, rows);
    finalize_kernel<<<1, 256, 0, stream>>>(ws, out);
}